// Round 4
// baseline (11745.565 us; speedup 1.0000x reference)
//
#include <hip/hip_runtime.h>
#include <stdint.h>

typedef unsigned short u16;
typedef __attribute__((ext_vector_type(8))) short short8;
typedef __attribute__((ext_vector_type(4))) float f32x4;

__device__ __forceinline__ float bf2f(u16 u){
    union { uint32_t i; float f; } x; x.i = ((uint32_t)u)<<16; return x.f;
}
__device__ __forceinline__ u16 f2bf(float f){
    union { float f; uint32_t i; } x; x.f = f;
    uint32_t u = x.i + 0x7FFFu + ((x.i>>16)&1u);   // RNE
    return (u16)(u>>16);
}
// v = hi + mid + lo, each bf16; residuals are exact f32 subtractions
__device__ __forceinline__ void split3(float v, u16& hi, u16& mid, u16& lo){
    hi = f2bf(v);            float r  = v - bf2f(hi);
    mid = f2bf(r);           float r2 = r - bf2f(mid);
    lo = f2bf(r2);
}
__device__ __forceinline__ void split2(float v, u16& hi, u16& mid){
    hi = f2bf(v);  mid = f2bf(v - bf2f(hi));
}

#define MFMA __builtin_amdgcn_mfma_f32_16x16x32_bf16

// ---------------- fused recurrent kernel, near-f32 numerics ----------------
// 256 blocks = 16 groups (16 batch rows) x 16 col-blocks (32 cols).
// Wave wv: gate = wv>>1 (0: c-gate/W_c, 1: a-gate/W_a), half = wv&1 (16-col half).
// Weights resident in VGPRs as 2-way bf16 (hi+mid, rep err 2^-17).
// h carried as 3-way bf16 (rep err 2^-26), double-buffered in ws.
// Per matrix 5 MFMA chains keep all product terms >= 2^-16.
__global__ __launch_bounds__(256,1)
void rec_fused(const float* __restrict__ x,  const float* __restrict__ h0,
               const float* __restrict__ Wc, const float* __restrict__ Wa,
               const float* __restrict__ Uc, const float* __restrict__ Ua, const float* __restrict__ Uh,
               const float* __restrict__ bc, const float* __restrict__ ba, const float* __restrict__ bh,
               float* __restrict__ out,
               u16* __restrict__ hhi, u16* __restrict__ hmd, u16* __restrict__ hlo,
               unsigned int* __restrict__ cnt)
{
    const int tid  = threadIdx.x;
    const int bid  = blockIdx.x;
    const int g    = bid & 15;      // batch-row group (blocks g+16k land on XCD g&7)
    const int cb   = bid >> 4;      // col-block 0..15
    const int lane = tid & 63;
    const int wv   = tid >> 6;
    const int gate = wv >> 1;
    const int half = wv & 1;
    const int n16  = lane & 15;
    const int q    = lane >> 4;
    const int b0   = g * 16;
    const int j0   = cb * 32;
    const int jw   = j0 + half*16;

    __shared__ float accC[2][16][16];
    __shared__ float accA[2][16][16];
    __shared__ float xpre[3][2][16][16];

    // ---- resident weight fragments, 2-way split ----
    // B-operand: lane n16 = output col jw+n16, k = kk*32 + q*8 + i
    const float* Wg = gate ? Wa : Wc;
    short8 wfh[16], wfm[16];
    #pragma unroll
    for (int kk=0;kk<16;++kk){
        const float* p = Wg + (size_t)(jw + n16)*512 + kk*32 + q*8;
        #pragma unroll
        for (int i=0;i<8;++i){ u16 a,b; split2(p[i],a,b); wfh[kk][i]=(short)a; wfm[kk][i]=(short)b; }
    }
    const float* U0 = gate ? Ua : Uc;    // primary U for this gate
    short8 u0h[8], u0m[8], u1h[8], u1m[8];
    #pragma unroll
    for (int kk=0;kk<8;++kk){
        const float* p = U0 + (size_t)(jw + n16)*256 + kk*32 + q*8;
        #pragma unroll
        for (int i=0;i<8;++i){ u16 a,b; split2(p[i],a,b); u0h[kk][i]=(short)a; u0m[kk][i]=(short)b; }
        const float* p2 = Uh + (size_t)(jw + n16)*256 + kk*32 + q*8;
        #pragma unroll
        for (int i=0;i<8;++i){ u16 a,b; split2(p2[i],a,b); u1h[kk][i]=(short)a; u1m[kk][i]=(short)b; }
    }

    // ---- init h buffer 0: 3-way split of f32 h0 ----
    if (cb == 0) {
        for (int i = tid; i < 16*512; i += 256) {
            int m = i >> 9, k = i & 511;
            size_t o = (size_t)(b0+m)*512 + k;
            u16 a,b,c; split3(h0[o], a,b,c);
            hhi[o]=a; hmd[o]=b; hlo[o]=c;
        }
    }

    unsigned int* cg = cnt + g*32;   // 128B-spaced per-group counters
    unsigned int phase = 1;
    __syncthreads();
    if (tid == 0) {
        __threadfence();
        atomicAdd(cg, 1u);
        while (__hip_atomic_load(cg, __ATOMIC_RELAXED, __HIP_MEMORY_SCOPE_AGENT) < 16u*phase)
            __builtin_amdgcn_s_sleep(2);
        __threadfence();
    }
    __syncthreads();

    const int rp = gate * 2;

    #pragma unroll 1
    for (int t = 0; t < 512; ++t) {
        const size_t cur = (size_t)(t & 1) * (256*512);
        const size_t nxt = (size_t)((t+1) & 1) * (256*512);

        // ---- x projections: A[m=n16][k=q*8+i], x split 3-way on the fly ----
        f32x4 z = (f32x4){0.f,0.f,0.f,0.f};
        f32x4 p0=z,p1=z,p2=z,p3=z, q0=z,q1=z,q2=z,q3=z;
        #pragma unroll
        for (int kk=0;kk<8;++kk){
            const float* xp = x + ((size_t)t*256 + b0 + n16)*256 + kk*32 + q*8;
            short8 xh_, xm_, xl_;
            #pragma unroll
            for (int i=0;i<8;++i){ u16 a,b,c; split3(xp[i],a,b,c); xh_[i]=(short)a; xm_[i]=(short)b; xl_[i]=(short)c; }
            p0 = MFMA(xh_, u0h[kk], p0, 0,0,0);
            p1 = MFMA(xh_, u0m[kk], p1, 0,0,0);
            p2 = MFMA(xm_, u0h[kk], p2, 0,0,0);
            p3 = MFMA(xm_, u0m[kk], p3, 0,0,0);
            p0 = MFMA(xl_, u0h[kk], p0, 0,0,0);
            if (gate == 1) {          // wave-uniform
                q0 = MFMA(xh_, u1h[kk], q0, 0,0,0);
                q1 = MFMA(xh_, u1m[kk], q1, 0,0,0);
                q2 = MFMA(xm_, u1h[kk], q2, 0,0,0);
                q3 = MFMA(xm_, u1m[kk], q3, 0,0,0);
                q0 = MFMA(xl_, u1h[kk], q0, 0,0,0);
            }
        }
        f32x4 xp0, xp1;
        #pragma unroll
        for (int r=0;r<4;++r){ xp0[r]=(p0[r]+p1[r])+(p2[r]+p3[r]); xp1[r]=(q0[r]+q1[r])+(q2[r]+q3[r]); }

        // ---- h GEMM: 5 chains (hi*Whi, hi*Wmid, mid*Whi, mid*Wmid, lo*Whi) ----
        f32x4 a0=z,a1=z,a2=z,a3=z;
        #pragma unroll
        for (int kk=0;kk<16;++kk){
            size_t o = cur + (size_t)(b0 + n16)*512 + kk*32 + q*8;
            short8 hh = *(const short8*)(hhi + o);
            short8 hm = *(const short8*)(hmd + o);
            short8 hl = *(const short8*)(hlo + o);
            a0 = MFMA(hh, wfh[kk], a0, 0,0,0);
            a1 = MFMA(hh, wfm[kk], a1, 0,0,0);
            a2 = MFMA(hm, wfh[kk], a2, 0,0,0);
            a3 = MFMA(hm, wfm[kk], a3, 0,0,0);
            a1 = MFMA(hl, wfh[kk], a1, 0,0,0);
        }

        // ---- stash in LDS (C/D: row=q*4+r, col=n16) ----
        #pragma unroll
        for (int r=0;r<4;++r) {
            float v = (a0[r]+a1[r]) + (a2[r]+a3[r]);
            if (gate == 0) accC[half][q*4+r][n16] = v;
            else           accA[half][q*4+r][n16] = v;
            xpre[gate][half][q*4+r][n16] = xp0[r];
            if (gate == 1) xpre[2][half][q*4+r][n16] = xp1[r];
        }
        __syncthreads();

        // ---- epilogue: each wave covers (col-half wv&1, rows q*4+rp+e) ----
        #pragma unroll
        for (int e=0;e<2;++e) {
            const int row = q*4 + rp + e;
            const int b   = b0 + row;
            const int j   = j0 + half*16 + n16;
            const float cpre = accC[half][row][n16];
            const float apre = accA[half][row][n16];
            const float xc = xpre[0][half][row][n16] + bc[j];
            const float xa = xpre[1][half][row][n16] + ba[j];
            const float xh = xpre[2][half][row][n16] + bh[j];
            const size_t hb = (size_t)b*512 + j;
            const float hf = bf2f(hhi[cur+hb]) + (bf2f(hmd[cur+hb]) + bf2f(hlo[cur+hb]));

            const float cv = 1.f/(1.f + __expf(-(cpre + xc)));        // sigmoid
            const float av = 2.f/(1.f + __expf(-2.f*(apre + xa)));    // 1 + tanh
            const float zz = xh + av*hf;
            const float th = 2.f/(1.f + __expf(-2.f*zz)) - 1.f;       // tanh
            const float hn = cv*hf + (1.f - cv)*th;

            u16 sh, sm, sl; split3(hn, sh, sm, sl);
            hhi[nxt+hb]=sh; hmd[nxt+hb]=sm; hlo[nxt+hb]=sl;
            out[((size_t)t*256 + b)*512 + j] = hn;                    // y_seq (f32)
            if (t == 511) out[(size_t)67108864 + hb] = hn;            // hn (f32)
        }

        ++phase;
        __syncthreads();
        if (tid == 0) {
            __threadfence();
            atomicAdd(cg, 1u);
            while (__hip_atomic_load(cg, __ATOMIC_RELAXED, __HIP_MEMORY_SCOPE_AGENT) < 16u*phase)
                __builtin_amdgcn_s_sleep(2);
            __threadfence();
        }
        __syncthreads();
    }
}

// ---------------- launch ----------------
extern "C" void kernel_launch(void* const* d_in, const int* in_sizes, int n_in,
                              void* d_out, int out_size, void* d_ws, size_t ws_size,
                              hipStream_t stream)
{
    (void)in_sizes; (void)n_in; (void)out_size; (void)ws_size;
    const float* x  = (const float*)d_in[0];
    const float* h0 = (const float*)d_in[1];
    const float* Uc = (const float*)d_in[2];
    const float* Wc = (const float*)d_in[3];
    const float* bc = (const float*)d_in[4];
    const float* Ua = (const float*)d_in[5];
    const float* Wa = (const float*)d_in[6];
    const float* ba = (const float*)d_in[7];
    const float* Uh = (const float*)d_in[8];
    const float* bh = (const float*)d_in[9];
    float* out = (float*)d_out;

    char* ws = (char*)d_ws;
    unsigned int* cnt = (unsigned int*)ws;                 // 16 counters, 128B apart
    u16* hhi = (u16*)(ws + 2048);                          // each: 2 x (256,512) bf16
    u16* hmd = hhi + (size_t)2*256*512;
    u16* hlo = hmd + (size_t)2*256*512;
    // total ws use: 2048 + 3*2*262144*2 = ~3.1 MB

    hipMemsetAsync(cnt, 0, 2048, stream);                  // counters MUST start at 0

    rec_fused<<<256, 256, 0, stream>>>(x, h0, Wc, Wa, Uc, Ua, Uh, bc, ba, bh,
                                       out, hhi, hmd, hlo, cnt);
}